// Round 1
// baseline (1489.038 us; speedup 1.0000x reference)
//
#include <hip/hip_runtime.h>
#include <cstdint>
#include <cstddef>

#define NB 4
#define NN 1000
#define NPAD 1024
#define HW 65536          // 256*256 pixels per mask
#define MAXDET 100
#define MIN_SIZE 25.0f
#define IOU_T 0.3f
#define PARTS 4           // blocks per mask copy
#define PART_F4 (HW / 4 / PARTS)   // float4 elements per part = 4096

// Flat output layout (floats), concatenated in reference return order:
// boxes [4,100,4], masks [4,100,1,256,256], scores [4,100], labels [4,100], valid [4,100]
#define OFF_BOXES  0
#define OFF_MASKS  (NB * MAXDET * 4)
#define OFF_SCORES (OFF_MASKS + (size_t)NB * MAXDET * HW)
#define OFF_LABELS (OFF_SCORES + NB * MAXDET)
#define OFF_VALID  (OFF_LABELS + NB * MAXDET)

__global__ __launch_bounds__(256) void nms_kernel(
    const float* __restrict__ boxes,    // [B,N,4]
    const float* __restrict__ scores,   // [B,N]
    const int*   __restrict__ labels,   // [B,N]
    float* __restrict__ out,            // flat output buffer
    int*   __restrict__ sel)            // [B*MAXDET] selected original indices (-1 = empty)
{
    __shared__ float s_score[NPAD];
    __shared__ int   s_idx[NPAD];
    __shared__ float sx1[NPAD], sy1[NPAD], sx2[NPAD], sy2[NPAD], sar[NPAD];
    __shared__ int   alive[NPAD];       // valid & ~suppressed
    __shared__ int   s_scan[256];

    const int b   = blockIdx.x;
    const int tid = threadIdx.x;
    const float* bboxes  = boxes  + (size_t)b * NN * 4;
    const float* bscores = scores + (size_t)b * NN;
    const int*   blabels = labels + (size_t)b * NN;

    // ---- load: masked scores (invalid area -> -inf), identity index ----
    for (int e = tid; e < NPAD; e += 256) {
        float sc = -INFINITY;
        if (e < NN) {
            float x1 = bboxes[e * 4 + 0], y1 = bboxes[e * 4 + 1];
            float x2 = bboxes[e * 4 + 2], y2 = bboxes[e * 4 + 3];
            float area = (x2 - x1) * (y2 - y1);
            if (area > MIN_SIZE) sc = bscores[e];
        }
        s_score[e] = sc;
        s_idx[e]   = e;
    }
    __syncthreads();

    // ---- bitonic sort: descending score, tie-break ascending original index
    //      (matches stable jnp.argsort(-masked_scores)) ----
    for (int k = 2; k <= NPAD; k <<= 1) {
        for (int j = k >> 1; j > 0; j >>= 1) {
            for (int e = tid; e < NPAD; e += 256) {
                int ixj = e ^ j;
                if (ixj > e) {
                    float sa = s_score[e], sb = s_score[ixj];
                    int   ia = s_idx[e],   ib = s_idx[ixj];
                    bool a_first = (sa > sb) || (sa == sb && ia < ib);
                    bool up = ((e & k) == 0);
                    if (up ? !a_first : a_first) {
                        s_score[e] = sb; s_score[ixj] = sa;
                        s_idx[e]   = ib; s_idx[ixj]   = ia;
                    }
                }
            }
            __syncthreads();
        }
    }

    // ---- gather sorted boxes into SoA (conflict-free LDS), init alive ----
    for (int e = tid; e < NPAD; e += 256) {
        int fi = s_idx[e];
        float x1 = 0.f, y1 = 0.f, x2 = 0.f, y2 = 0.f, area = 0.f;
        int al = 0;
        if (fi < NN) {
            x1 = bboxes[fi * 4 + 0]; y1 = bboxes[fi * 4 + 1];
            x2 = bboxes[fi * 4 + 2]; y2 = bboxes[fi * 4 + 3];
            area = (x2 - x1) * (y2 - y1);
            al = (area > MIN_SIZE) ? 1 : 0;
        }
        sx1[e] = x1; sy1[e] = y1; sx2[e] = x2; sy2[e] = y2; sar[e] = area;
        alive[e] = al;
    }
    __syncthreads();

    // ---- greedy NMS: sequential over sorted order; parallel suppression ----
    for (int i = 0; i < NN; ++i) {
        if (alive[i]) {               // uniform branch (same LDS address)
            float ix1 = sx1[i], iy1 = sy1[i], ix2 = sx2[i], iy2 = sy2[i];
            float ia = sar[i];
            for (int j = i + 1 + tid; j < NN; j += 256) {
                float ltx = fmaxf(ix1, sx1[j]);
                float lty = fmaxf(iy1, sy1[j]);
                float rbx = fminf(ix2, sx2[j]);
                float rby = fminf(iy2, sy2[j]);
                float w = fmaxf(rbx - ltx, 0.0f);
                float h = fmaxf(rby - lty, 0.0f);
                float inter = w * h;
                float denom = ia + sar[j] - inter;
                float iou = (denom > 0.0f) ? (inter / denom) : 0.0f;
                if (iou > IOU_T) alive[j] = 0;
            }
            __syncthreads();
        }
    }

    // ---- compaction: blocked scan (4 elements/thread) over alive ----
    int base = tid * 4;
    int l0 = alive[base + 0], l1 = alive[base + 1];
    int l2 = alive[base + 2], l3 = alive[base + 3];
    int lsum = l0 + l1 + l2 + l3;
    s_scan[tid] = lsum;
    __syncthreads();
    for (int off = 1; off < 256; off <<= 1) {
        int v = (tid >= off) ? s_scan[tid - off] : 0;
        __syncthreads();
        s_scan[tid] += v;
        __syncthreads();
    }
    int total = s_scan[255];
    int r = s_scan[tid] - lsum;    // exclusive prefix for this thread's chunk

    float* out_boxes  = out + OFF_BOXES;
    float* out_scores = out + OFF_SCORES;
    float* out_labels = out + OFF_LABELS;
    float* out_valid  = out + OFF_VALID;

    #pragma unroll
    for (int q = 0; q < 4; ++q) {
        int al = (q == 0) ? l0 : (q == 1) ? l1 : (q == 2) ? l2 : l3;
        if (al) {
            if (r < MAXDET) {
                int e = base + q;
                int fi = s_idx[e];
                int slot = b * MAXDET + r;
                sel[slot] = fi;
                out_boxes[slot * 4 + 0] = bboxes[fi * 4 + 0];
                out_boxes[slot * 4 + 1] = bboxes[fi * 4 + 1];
                out_boxes[slot * 4 + 2] = bboxes[fi * 4 + 2];
                out_boxes[slot * 4 + 3] = bboxes[fi * 4 + 3];
                out_scores[slot] = bscores[fi];
                out_labels[slot] = (float)blabels[fi];
                out_valid[slot]  = 1.0f;
            }
            r++;
        }
    }

    // ---- fill empty slots (output is re-poisoned before every call) ----
    int count = (total < MAXDET) ? total : MAXDET;
    for (int k2 = tid; k2 < MAXDET; k2 += 256) {
        if (k2 >= count) {
            int slot = b * MAXDET + k2;
            sel[slot] = -1;
            out_boxes[slot * 4 + 0] = 0.0f;
            out_boxes[slot * 4 + 1] = 0.0f;
            out_boxes[slot * 4 + 2] = 0.0f;
            out_boxes[slot * 4 + 3] = 0.0f;
            out_scores[slot] = 0.0f;
            out_labels[slot] = -1.0f;
            out_valid[slot]  = 0.0f;
        }
    }
}

__global__ __launch_bounds__(256) void gather_masks(
    const float* __restrict__ masks,    // [B,N,1,256,256]
    const int*   __restrict__ sel,      // [B*MAXDET]
    float* __restrict__ out_masks)      // [B,MAXDET,1,256,256]
{
    int blk  = blockIdx.x;
    int slot = blk / PARTS;
    int part = blk % PARTS;
    int b    = slot / MAXDET;
    int fi   = sel[slot];

    float4* dst = (float4*)out_masks + (size_t)slot * (HW / 4) + (size_t)part * PART_F4;
    if (fi >= 0) {
        const float4* src = (const float4*)masks
                          + (size_t)(b * NN + fi) * (HW / 4) + (size_t)part * PART_F4;
        for (int t = threadIdx.x; t < PART_F4; t += 256) dst[t] = src[t];
    } else {
        float4 z = make_float4(0.f, 0.f, 0.f, 0.f);
        for (int t = threadIdx.x; t < PART_F4; t += 256) dst[t] = z;
    }
}

extern "C" void kernel_launch(void* const* d_in, const int* in_sizes, int n_in,
                              void* d_out, int out_size, void* d_ws, size_t ws_size,
                              hipStream_t stream) {
    const float* boxes  = (const float*)d_in[0];
    const float* masks  = (const float*)d_in[1];
    const float* scores = (const float*)d_in[2];
    const int*   labels = (const int*)d_in[3];
    float* out = (float*)d_out;
    int*   sel = (int*)d_ws;

    nms_kernel<<<NB, 256, 0, stream>>>(boxes, scores, labels, out, sel);
    gather_masks<<<NB * MAXDET * PARTS, 256, 0, stream>>>(masks, sel, out + OFF_MASKS);
}

// Round 2
// 1439.775 us; speedup vs baseline: 1.0342x; 1.0342x over previous
//
#include <hip/hip_runtime.h>
#include <cstdint>
#include <cstddef>

#define NB 4
#define NN 1000
#define NPAD 1024
#define HW 65536          // 256*256 pixels per mask
#define MAXDET 100
#define MIN_SIZE 25.0f
#define IOU_T 0.3f
#define PARTS 8           // blocks per mask copy
#define PART_F4 (HW / 4 / PARTS)   // 2048 float4 per part

// Flat output layout (floats), concatenated in reference return order:
// boxes [4,100,4], masks [4,100,1,256,256], scores [4,100], labels [4,100], valid [4,100]
#define OFF_BOXES  0
#define OFF_MASKS  (NB * MAXDET * 4)
#define OFF_SCORES (OFF_MASKS + (size_t)NB * MAXDET * HW)
#define OFF_LABELS (OFF_SCORES + NB * MAXDET)
#define OFF_VALID  (OFF_LABELS + NB * MAXDET)

// ws layout: sel[400] ints at 0; suppression bitmasks at +2048:
// g_mask[b][i][w] : b<4, i<1000 (sorted row), w<16 (u64 word over sorted cols)
#define WS_MASK_OFF 2048

__global__ __launch_bounds__(1024) void nms_all(
    const float* __restrict__ boxes,    // [B,N,4]
    const float* __restrict__ scores,   // [B,N]
    const int*   __restrict__ labels,   // [B,N]
    float* __restrict__ out,            // flat output buffer
    int*   __restrict__ sel,            // [B*MAXDET]
    unsigned long long* __restrict__ g_mask_all)  // [B][1000][16]
{
    __shared__ float  s_score[NPAD];
    __shared__ int    s_idx[NPAD];
    __shared__ float4 s_box[NPAD];
    __shared__ float  s_area[NPAD];
    __shared__ unsigned long long s_validbits[16];
    __shared__ unsigned long long s_sup[16];
    __shared__ int    s_wsum[16];
    __shared__ int    s_woff[17];

    const int b   = blockIdx.x;
    const int tid = threadIdx.x;
    const int wv  = tid >> 6;          // wave id 0..15
    const int lane = tid & 63;

    const float4* bb4   = (const float4*)(boxes + (size_t)b * NN * 4);
    const float*  bsc   = scores + (size_t)b * NN;
    const int*    blb   = labels + (size_t)b * NN;
    unsigned long long* gm = g_mask_all + (size_t)b * NN * 16;

    // ---- phase 1: masked scores + identity idx; zero-fill mask region ----
    {
        float sc = -INFINITY;
        if (tid < NN) {
            float4 v = bb4[tid];
            float a = (v.z - v.x) * (v.w - v.y);
            if (a > MIN_SIZE) sc = bsc[tid];
        }
        s_score[tid] = sc;
        s_idx[tid]   = tid;
        for (int t = tid; t < NN * 16; t += 1024) gm[t] = 0ull;
    }

    // ---- phase 2: bitonic sort, descending score, tie-break ascending idx ----
    for (int k = 2; k <= NPAD; k <<= 1) {
        for (int j = k >> 1; j > 0; j >>= 1) {
            __syncthreads();
            int ixj = tid ^ j;
            if (ixj > tid) {
                float sa = s_score[tid], sb = s_score[ixj];
                int   ia = s_idx[tid],   ib = s_idx[ixj];
                bool a_first = (sa > sb) || (sa == sb && ia < ib);
                bool up = ((tid & k) == 0);
                if (up ? !a_first : a_first) {
                    s_score[tid] = sb; s_score[ixj] = sa;
                    s_idx[tid]   = ib; s_idx[ixj]   = ia;
                }
            }
        }
    }
    __syncthreads();

    // ---- phase 3: gather sorted boxes (SoA), validity ballot ----
    {
        int fi = s_idx[tid];
        float4 bx = make_float4(0.f, 0.f, 0.f, 0.f);
        float ar = 0.f;
        bool val = false;
        if (fi < NN) {
            bx = bb4[fi];
            ar = (bx.z - bx.x) * (bx.w - bx.y);
            val = ar > MIN_SIZE;
        }
        s_box[tid] = bx;
        s_area[tid] = ar;
        unsigned long long vb = __ballot(val);
        if (lane == 0) s_validbits[wv] = vb;
    }
    __syncthreads();

    // ---- phase 4: suppression bitmask build (upper triangle, balanced) ----
    // pair p -> (rb, w), rb<=w<16; row i = rb*64+lane; word w covers cols w*64..w*64+63
    for (int p = wv; p < 136; p += 16) {
        int rb = 0, base = 0;
        while (base + 16 - rb <= p) { base += 16 - rb; ++rb; }
        int w = rb + (p - base);
        int i = (rb << 6) + lane;
        float4 bi = s_box[i];
        float  ai = s_area[i];
        unsigned long long m = 0ull;
        int jb = w << 6;
        for (int j2 = 0; j2 < 64; ++j2) {
            int j = jb + j2;
            float4 bj = s_box[j];          // same addr across wave -> broadcast
            float  aj = s_area[j];
            float ltx = fmaxf(bi.x, bj.x);
            float lty = fmaxf(bi.y, bj.y);
            float rbx = fminf(bi.z, bj.z);
            float rby = fminf(bi.w, bj.w);
            float cw = fmaxf(rbx - ltx, 0.0f);
            float ch = fmaxf(rby - lty, 0.0f);
            float inter = cw * ch;
            float den = ai + aj - inter;
            float iou = (den > 0.0f) ? (inter / den) : 0.0f;  // exact ref arithmetic
            m |= (unsigned long long)((iou > IOU_T) && (j > i)) << j2;
        }
        if (i < NN) gm[(size_t)i * 16 + w] = m;
    }
    __syncthreads();   // gm visible block-wide

    // ---- phase 5: greedy walk, single wave, barrier-free, depth-4 prefetch ----
    if (tid < 64) {
        const bool lw = lane < 16;       // lanes 0..15 own sup words
        unsigned long long sup = 0ull;
        unsigned long long pre0 = lw ? gm[(size_t)0 * 16 + lane] : 0ull;
        unsigned long long pre1 = lw ? gm[(size_t)1 * 16 + lane] : 0ull;
        unsigned long long pre2 = lw ? gm[(size_t)2 * 16 + lane] : 0ull;
        unsigned long long pre3 = lw ? gm[(size_t)3 * 16 + lane] : 0ull;
        for (int c = 0; c < 16; ++c) {
            unsigned long long supw = __shfl(sup, c);
            unsigned long long vw = s_validbits[c];
            const int nb = (c == 15) ? (NN - 15 * 64) : 64;   // 40 on last chunk
            for (int bit = 0; bit < nb; bit += 4) {
#define STEP(PH, B) { \
                int i = (c << 6) + bit + (B); \
                unsigned long long row = PH; \
                int nx = i + 4; if (nx >= NN) nx = NN - 1; \
                PH = lw ? gm[(size_t)nx * 16 + lane] : 0ull; \
                if (((vw >> (bit + (B))) & 1ull) && !((supw >> (bit + (B))) & 1ull)) { \
                    sup |= row; \
                    supw = __shfl(sup, c); \
                } }
                STEP(pre0, 0)
                STEP(pre1, 1)
                STEP(pre2, 2)
                STEP(pre3, 3)
#undef STEP
            }
        }
        if (lw) s_sup[lane] = sup;
    }
    __syncthreads();

    // ---- phase 6: compaction via ballot-scan, write small outputs ----
    unsigned long long vwd = s_validbits[wv];
    unsigned long long swd = s_sup[wv];
    bool kp = (((vwd >> lane) & 1ull) != 0) && (((swd >> lane) & 1ull) == 0);
    unsigned long long bal = __ballot(kp);
    int lprefix = __popcll(bal & ((1ull << lane) - 1ull));
    if (lane == 0) s_wsum[wv] = __popcll(bal);
    __syncthreads();
    if (tid == 0) {
        int s = 0;
        for (int q = 0; q < 16; ++q) { s_woff[q] = s; s += s_wsum[q]; }
        s_woff[16] = s;
    }
    __syncthreads();
    int rank  = s_woff[wv] + lprefix;
    int total = s_woff[16];

    float* out_boxes  = out + OFF_BOXES;
    float* out_scores = out + OFF_SCORES;
    float* out_labels = out + OFF_LABELS;
    float* out_valid  = out + OFF_VALID;
    const int slot_base = b * MAXDET;

    if (kp && rank < MAXDET) {
        int slot = slot_base + rank;
        int fi = s_idx[tid];
        sel[slot] = fi;
        ((float4*)out_boxes)[slot] = s_box[tid];     // == boxes[fi]
        out_scores[slot] = s_score[tid];             // == scores[fi] (valid)
        out_labels[slot] = (float)blb[fi];
        out_valid[slot]  = 1.0f;
    }
    int count = total < MAXDET ? total : MAXDET;
    if (tid >= count && tid < MAXDET) {
        int slot = slot_base + tid;
        sel[slot] = -1;
        ((float4*)out_boxes)[slot] = make_float4(0.f, 0.f, 0.f, 0.f);
        out_scores[slot] = 0.0f;
        out_labels[slot] = -1.0f;
        out_valid[slot]  = 0.0f;
    }
}

__global__ __launch_bounds__(256) void gather_masks(
    const float* __restrict__ masks,    // [B,N,1,256,256]
    const int*   __restrict__ sel,      // [B*MAXDET]
    float* __restrict__ out_masks)      // [B,MAXDET,1,256,256]
{
    int blk  = blockIdx.x;
    int slot = blk / PARTS;
    int part = blk % PARTS;
    int b    = slot / MAXDET;
    int fi   = sel[slot];

    float4* dst = (float4*)out_masks + (size_t)slot * (HW / 4) + (size_t)part * PART_F4;
    if (fi >= 0) {
        const float4* src = (const float4*)masks
                          + (size_t)(b * NN + fi) * (HW / 4) + (size_t)part * PART_F4;
        for (int t = threadIdx.x; t < PART_F4; t += 256) dst[t] = src[t];
    } else {
        float4 z = make_float4(0.f, 0.f, 0.f, 0.f);
        for (int t = threadIdx.x; t < PART_F4; t += 256) dst[t] = z;
    }
}

extern "C" void kernel_launch(void* const* d_in, const int* in_sizes, int n_in,
                              void* d_out, int out_size, void* d_ws, size_t ws_size,
                              hipStream_t stream) {
    const float* boxes  = (const float*)d_in[0];
    const float* masks  = (const float*)d_in[1];
    const float* scores = (const float*)d_in[2];
    const int*   labels = (const int*)d_in[3];
    float* out = (float*)d_out;
    int*   sel = (int*)d_ws;
    unsigned long long* g_mask = (unsigned long long*)((char*)d_ws + WS_MASK_OFF);

    nms_all<<<NB, 1024, 0, stream>>>(boxes, scores, labels, out, sel, g_mask);
    gather_masks<<<NB * MAXDET * PARTS, 256, 0, stream>>>(masks, sel, out + OFF_MASKS);
}